// Round 1
// baseline (9.329 us; speedup 1.0000x reference)
//
#include <hip/hip_runtime.h>
#include <hip/hip_bf16.h>

#define CARD 50
#define NPAIRS (2 * CARD)   // 100 output distances
#define D 64                // feature dim

// One 64-lane wave per pair. Lane l holds dimension l of both rows.
// Butterfly shuffle-reduce across the full wave (width 64 on CDNA).
__global__ void rips_pairs_kernel(const float* __restrict__ X,
                                  const int* __restrict__ ids,
                                  float* __restrict__ out) {
    const int pair = blockIdx.x;          // 0 .. NPAIRS-1
    const int lane = threadIdx.x;         // 0 .. 63
    if (pair >= NPAIRS) return;

    const int i = ids[2 * pair];
    const int j = ids[2 * pair + 1];

    const float xi = X[(size_t)i * D + lane];
    const float xj = X[(size_t)j * D + lane];

    float sqi = xi * xi;
    float sqj = xj * xj;
    float dot = xi * xj;

    // 64-lane butterfly reduction (wave = 64 on gfx950)
    #pragma unroll
    for (int off = 32; off > 0; off >>= 1) {
        sqi += __shfl_xor(sqi, off, 64);
        sqj += __shfl_xor(sqj, off, 64);
        dot += __shfl_xor(dot, off, 64);
    }

    if (lane == 0) {
        // Match reference semantics:
        //   d2 = max(sq_i + sq_j - 2*dot, 0); pos = d2 > 0;
        //   d  = pos ? sqrt(d2) : 0
        float d2 = sqi + sqj - 2.0f * dot;
        d2 = fmaxf(d2, 0.0f);
        out[pair] = (d2 > 0.0f) ? sqrtf(d2) : 0.0f;
    }
}

extern "C" void kernel_launch(void* const* d_in, const int* in_sizes, int n_in,
                              void* d_out, int out_size, void* d_ws, size_t ws_size,
                              hipStream_t stream) {
    const float* X   = (const float*)d_in[0];   // [8192, 64] fp32
    const int*   ids = (const int*)d_in[1];     // [4*CARD] int32
    float* out = (float*)d_out;                 // [CARD, 2] fp32 = 100 floats

    rips_pairs_kernel<<<NPAIRS, 64, 0, stream>>>(X, ids, out);
}